// Round 5
// baseline (1060.842 us; speedup 1.0000x reference)
//
#include <hip/hip_runtime.h>
#include <hip/hip_bf16.h>
#include <stdint.h>

// Problem constants
#define B_ROWS   8192
#define CTX_REAL 5124     // 4096 state + 4 task + 1024 action
#define CTX_PAD  5184     // padded to multiple of 64 (81*64), pad cols zeroed

typedef unsigned short u16;
typedef __attribute__((ext_vector_type(8))) short short8;
typedef __attribute__((ext_vector_type(16))) float f32x16;

#define AS1 __attribute__((address_space(1)))
#define AS3 __attribute__((address_space(3)))

__device__ __forceinline__ u16 f2bf(float f) {
    union { float f; uint32_t u; } v; v.f = f;
    uint32_t u = v.u;
    uint32_t r = 0x7fffu + ((u >> 16) & 1u);   // round-to-nearest-even
    return (u16)((u + r) >> 16);
}

// ---------------------------------------------------------------------------
// ctx = bf16([state | task_indicator | action | zeros]) , [B_ROWS][CTX_PAD]
// ---------------------------------------------------------------------------
__global__ void build_ctx(const float* __restrict__ state,
                          const float* __restrict__ ti,
                          const float* __restrict__ action,
                          u16* __restrict__ ctx) {
    const int row = blockIdx.y;
    const int c2  = blockIdx.x * blockDim.x + threadIdx.x;
    const int col = c2 * 2;
    if (col >= CTX_PAD) return;

    float v0, v1;
    {
        int c = col;
        v0 = (c < 4096) ? state[(size_t)row * 4096 + c]
           : (c < 4100) ? ti[(size_t)row * 4 + (c - 4096)]
           : (c < 5124) ? action[(size_t)row * 1024 + (c - 4100)]
           : 0.0f;
        c = col + 1;
        v1 = (c < 4096) ? state[(size_t)row * 4096 + c]
           : (c < 4100) ? ti[(size_t)row * 4 + (c - 4096)]
           : (c < 5124) ? action[(size_t)row * 1024 + (c - 4100)]
           : 0.0f;
    }
    uint32_t packed = (uint32_t)f2bf(v0) | ((uint32_t)f2bf(v1) << 16);
    *(uint32_t*)&ctx[(size_t)row * CTX_PAD + col] = packed;
}

// ---------------------------------------------------------------------------
// Wt[n][k] = bf16(W[k][n]) for k < K_real, else 0.   W: [K_real][N] fp32,
// Wt: [N][Kpad] bf16.  64x64 LDS-tiled transpose.
// ---------------------------------------------------------------------------
__global__ void wconv(const float* __restrict__ W, u16* __restrict__ Wt,
                      int K_real, int Kpad, int N) {
    __shared__ float tile[64][65];
    const int k0 = blockIdx.x * 64;
    const int n0 = blockIdx.y * 64;
    const int t  = threadIdx.x;
#pragma unroll
    for (int i = 0; i < 16; ++i) {
        int idx = i * 256 + t;
        int r = idx >> 6, c = idx & 63;       // r: k offset, c: n offset
        int k = k0 + r;
        tile[r][c] = (k < K_real) ? W[(size_t)k * N + n0 + c] : 0.0f;
    }
    __syncthreads();
#pragma unroll
    for (int i = 0; i < 16; ++i) {
        int idx = i * 256 + t;
        int rn = idx >> 6, ck = idx & 63;     // rn: n offset, ck: k offset
        Wt[(size_t)(n0 + rn) * Kpad + k0 + ck] = f2bf(tile[ck][rn]);
    }
}

// ---------------------------------------------------------------------------
// OLD 2-phase 128x128 template (verified R2, 956µs pipeline) — kept for L4.
// ---------------------------------------------------------------------------
template <int TM, int TN, int MW, int NW, bool OUT_BF16>
__global__ __launch_bounds__(256, 2)
void gemm_bias(const u16* __restrict__ A1, int lda1, int K1,
               const u16* __restrict__ A2, int lda2,
               const u16* __restrict__ Bt, int ldb, int Ktot,
               const float* __restrict__ bias,
               void* __restrict__ Cout, int ldc) {
    constexpr int FI = TM / MW / 32;
    constexpr int FJ = TN / NW / 32;
    __shared__ u16 tA[2][TM * 64];
    __shared__ u16 tB[2][TN * 64];

    const int t    = threadIdx.x;
    const int wave = t >> 6;
    const int lane = t & 63;
    const int l32  = lane & 31;
    const int half = lane >> 5;
    const int lswz = lane & 7;
    const int wr   = (wave / NW) * (TM / MW);
    const int wc   = (wave % NW) * (TN / NW);
    const int rowBase = blockIdx.x * TM;
    const int colBase = blockIdx.y * TN;

    const int srow = t >> 3;
    const int scol = ((t & 7) ^ (srow & 7)) * 8;

    const u16* gA1 = A1 + (size_t)(rowBase + srow) * lda1 + scol;
    const u16* gA2 = A2 ? (A2 + (size_t)(rowBase + srow) * lda2 + scol) : gA1;
    const u16* gB  = Bt + (size_t)(colBase + srow) * ldb + scol;

    f32x16 acc[FI][FJ] = {};

    const int nKt = Ktot >> 6;

    auto stage = [&](int kt, int buf) {
        const int k0 = kt << 6;
        const u16* srcA;
        int strideA;
        if (k0 < K1) { srcA = gA1 + k0;        strideA = lda1; }
        else         { srcA = gA2 + (k0 - K1); strideA = lda2; }
        const u16* srcB = gB + k0;
        char* ldsA = (char*)tA[buf] + wave * 1024;
        char* ldsB = (char*)tB[buf] + wave * 1024;
#pragma unroll
        for (int it = 0; it < TM / 32; ++it)
            __builtin_amdgcn_global_load_lds(
                (AS1 const void*)(srcA + (size_t)(it * 32) * strideA),
                (AS3 void*)(ldsA + it * 4096), 16, 0, 0);
#pragma unroll
        for (int it = 0; it < TN / 32; ++it)
            __builtin_amdgcn_global_load_lds(
                (AS1 const void*)(srcB + (size_t)(it * 32) * ldb),
                (AS3 void*)(ldsB + it * 4096), 16, 0, 0);
    };

    stage(0, 0);
    __syncthreads();

    for (int kt = 0; kt < nKt; ++kt) {
        const int buf = kt & 1;
        if (kt + 1 < nKt) stage(kt + 1, buf ^ 1);

        const u16* tAw = tA[buf] + wr * 64;
        const u16* tBw = tB[buf] + wc * 64;
#pragma unroll
        for (int ks = 0; ks < 4; ++ks) {
            const int kchunk = ks * 2 + half;
            const int swz    = (kchunk ^ lswz) * 8;
            short8 a[FI], b[FJ];
#pragma unroll
            for (int i = 0; i < FI; ++i)
                a[i] = *(const short8*)(tAw + (i * 32 + l32) * 64 + swz);
#pragma unroll
            for (int j = 0; j < FJ; ++j)
                b[j] = *(const short8*)(tBw + (j * 32 + l32) * 64 + swz);
#pragma unroll
            for (int i = 0; i < FI; ++i)
#pragma unroll
                for (int j = 0; j < FJ; ++j)
                    acc[i][j] = __builtin_amdgcn_mfma_f32_32x32x16_bf16(
                        a[i], b[j], acc[i][j], 0, 0, 0);
        }
        __syncthreads();
    }

    if (OUT_BF16) {
        u16* C = (u16*)Cout;
#pragma unroll
        for (int i = 0; i < FI; ++i) {
            const int rbase = rowBase + wr + i * 32 + 4 * half;
#pragma unroll
            for (int j = 0; j < FJ; ++j) {
                const int c = colBase + wc + j * 32 + l32;
                const float bb = bias[c];
#pragma unroll
                for (int reg = 0; reg < 16; ++reg) {
                    const int r = rbase + (reg & 3) + 8 * (reg >> 2);
                    C[(size_t)r * ldc + c] = f2bf(acc[i][j][reg] + bb);
                }
            }
        }
    } else {
        float* C = (float*)Cout;
#pragma unroll
        for (int i = 0; i < FI; ++i) {
            const int rbase = rowBase + wr + i * 32 + 4 * half;
#pragma unroll
            for (int j = 0; j < FJ; ++j) {
                const int c = colBase + wc + j * 32 + l32;
                const float bb = bias[c];
#pragma unroll
                for (int reg = 0; reg < 16; ++reg) {
                    const int r = rbase + (reg & 3) + 8 * (reg >> 2);
                    C[(size_t)r * ldc + c] = acc[i][j][reg] + bb;
                }
            }
        }
    }
}

// ---------------------------------------------------------------------------
// 8-wave counted-vmcnt template (T3+T4+T5).  512 threads, waves 2M x 4N,
// BK=64, double-buffered STATIC LDS (R4: was dynamic — dynamic >64KB needs a
// launch-attribute opt-in on HIP and risks a launch-config failure; static is
// compile-time checked against gfx950's 160KB), 2-deep prefetch.
// Per tile: gate s_waitcnt vmcnt(LPT) (never 0 except last tile) + raw
// s_barrier (no __syncthreads -> no compiler vmcnt(0) drain); 4 phases of
// {ds_read ks, setprio(1) MFMA cluster setprio(0), barrier}; restage the
// just-consumed buffer with tile kt+2 after the final phase barrier.
// vmcnt ledger: prologue issues 2*LPT; each iter-end issues LPT; gate
// vmcnt(LPT) at iter kt waits for tile kt's LPT oldest loads (tile kt+1's
// remain in flight).  Last iter gates vmcnt(0) (nothing staged behind it).
// Swizzle / MFMA layouts identical to the proven 2-phase template.
// ---------------------------------------------------------------------------
template <int BM, int BN, bool OUT_BF16>
__global__ __launch_bounds__(512, 2)
void gemm8(const u16* __restrict__ A1, int lda1, int K1,
           const u16* __restrict__ A2, int lda2,
           const u16* __restrict__ Bt, int ldb, int Ktot,
           const float* __restrict__ bias,
           void* __restrict__ Cout, int ldc) {
    constexpr int FI  = BM / 64;       // (BM/2)/32 fragments in M per wave
    constexpr int FJ  = BN / 128;      // (BN/4)/32 fragments in N per wave
    constexpr int LPA = BM / 64;       // global_load_lds per thread, A tile
    constexpr int LPB = BN / 64;
    constexpr int LPT = LPA + LPB;
    static_assert(LPT == 8 || LPT == 6, "vmcnt literal dispatch");

    __shared__ u16 tA[2][BM * 64];     // static: 2*BM*128 bytes
    __shared__ u16 tB[2][BN * 64];     // static: 2*BN*128 bytes

    const int t    = threadIdx.x;
    const int wave = t >> 6;               // 0..7
    const int lane = t & 63;
    const int l32  = lane & 31;
    const int half = lane >> 5;
    const int lswz = lane & 7;
    const int wr   = (wave >> 2) * (BM / 2);   // wave row offset (2 in M)
    const int wc   = (wave & 3) * (BN / 4);    // wave col offset (4 in N)
    const int rowBase = blockIdx.x * BM;
    const int colBase = blockIdx.y * BN;

    // staging: thread t covers row (t>>3) (+64 per round, 512 thr = 64 rows),
    // 8 bf16 at swizzled chunk ((t&7) ^ (row&7)); 64 | row-step keeps row&7.
    const int srow = t >> 3;                   // 0..63
    const int scol = ((t & 7) ^ (srow & 7)) * 8;

    const u16* gA1 = A1 + (size_t)(rowBase + srow) * lda1 + scol;
    const u16* gA2 = A2 ? (A2 + (size_t)(rowBase + srow) * lda2 + scol) : gA1;
    const u16* gB  = Bt + (size_t)(colBase + srow) * ldb + scol;

    auto stage = [&](int kt, int buf) {
        const int k0 = kt << 6;
        const u16* srcA;
        int strideA;
        if (k0 < K1) { srcA = gA1 + k0;        strideA = lda1; }
        else         { srcA = gA2 + (k0 - K1); strideA = lda2; }
        const u16* srcB = gB + k0;
        char* ldsA = (char*)tA[buf] + wave * 1024;
        char* ldsB = (char*)tB[buf] + wave * 1024;
#pragma unroll
        for (int it = 0; it < LPA; ++it)
            __builtin_amdgcn_global_load_lds(
                (AS1 const void*)(srcA + (size_t)(it * 64) * strideA),
                (AS3 void*)(ldsA + it * 8192), 16, 0, 0);
#pragma unroll
        for (int it = 0; it < LPB; ++it)
            __builtin_amdgcn_global_load_lds(
                (AS1 const void*)(srcB + (size_t)(it * 64) * ldb),
                (AS3 void*)(ldsB + it * 8192), 16, 0, 0);
    };

    f32x16 acc[FI][FJ] = {};

    const int nKt = Ktot >> 6;
    // prologue: 2-deep prefetch
    stage(0, 0);
    if (nKt > 1) stage(1, 1);

    for (int kt = 0; kt < nKt; ++kt) {
        const int buf = kt & 1;
        // gate: this wave's tile-kt loads complete (kt+1's stay in flight)
        if (kt == nKt - 1) {
            asm volatile("s_waitcnt vmcnt(0)" ::: "memory");
        } else if constexpr (LPT == 8) {
            asm volatile("s_waitcnt vmcnt(8)" ::: "memory");
        } else {
            asm volatile("s_waitcnt vmcnt(6)" ::: "memory");
        }
        __builtin_amdgcn_s_barrier();   // all waves' tile-kt loads landed

        const u16* tAw = tA[buf] + wr * 64;
        const u16* tBw = tB[buf] + wc * 64;
#pragma unroll
        for (int ks = 0; ks < 4; ++ks) {
            const int kchunk = ks * 2 + half;
            const int swz    = (kchunk ^ lswz) * 8;
            short8 a[FI], b[FJ];
#pragma unroll
            for (int i = 0; i < FI; ++i)
                a[i] = *(const short8*)(tAw + (i * 32 + l32) * 64 + swz);
#pragma unroll
            for (int j = 0; j < FJ; ++j)
                b[j] = *(const short8*)(tBw + (j * 32 + l32) * 64 + swz);
            __builtin_amdgcn_s_setprio(1);
#pragma unroll
            for (int i = 0; i < FI; ++i)
#pragma unroll
                for (int j = 0; j < FJ; ++j)
                    acc[i][j] = __builtin_amdgcn_mfma_f32_32x32x16_bf16(
                        a[i], b[j], acc[i][j], 0, 0, 0);
            __builtin_amdgcn_s_setprio(0);
            __builtin_amdgcn_s_barrier();   // phase lock; last one guards restage
        }

        if (kt + 2 < nKt) stage(kt + 2, buf);   // buf fully consumed above
    }

    // epilogue: C/D col = lane&31, row = (reg&3) + 8*(reg>>2) + 4*half
    if (OUT_BF16) {
        u16* C = (u16*)Cout;
#pragma unroll
        for (int i = 0; i < FI; ++i) {
            const int rbase = rowBase + wr + i * 32 + 4 * half;
#pragma unroll
            for (int j = 0; j < FJ; ++j) {
                const int c = colBase + wc + j * 32 + l32;
                const float bb = bias[c];
#pragma unroll
                for (int reg = 0; reg < 16; ++reg) {
                    const int r = rbase + (reg & 3) + 8 * (reg >> 2);
                    C[(size_t)r * ldc + c] = f2bf(acc[i][j][reg] + bb);
                }
            }
        }
    } else {
        float* C = (float*)Cout;
#pragma unroll
        for (int i = 0; i < FI; ++i) {
            const int rbase = rowBase + wr + i * 32 + 4 * half;
#pragma unroll
            for (int j = 0; j < FJ; ++j) {
                const int c = colBase + wc + j * 32 + l32;
                const float bb = bias[c];
#pragma unroll
                for (int reg = 0; reg < 16; ++reg) {
                    const int r = rbase + (reg & 3) + 8 * (reg >> 2);
                    C[(size_t)r * ldc + c] = acc[i][j][reg] + bb;
                }
            }
        }
    }
}

// ---------------------------------------------------------------------------
extern "C" void kernel_launch(void* const* d_in, const int* in_sizes, int n_in,
                              void* d_out, int out_size, void* d_ws, size_t ws_size,
                              hipStream_t stream) {
    const float* state  = (const float*)d_in[0];
    const float* action = (const float*)d_in[1];
    const float* ti     = (const float*)d_in[2];
    // cx branches (d_in[3..18]) are dead wrt output — skipped.
    const float* W_l1 = (const float*)d_in[19]; const float* b_l1 = (const float*)d_in[20];
    const float* W_l2 = (const float*)d_in[21]; const float* b_l2 = (const float*)d_in[22];
    const float* W_l3 = (const float*)d_in[23]; const float* b_l3 = (const float*)d_in[24];
    const float* W_l4 = (const float*)d_in[25]; const float* b_l4 = (const float*)d_in[26];
    const float* W_l5 = (const float*)d_in[27]; const float* b_l5 = (const float*)d_in[28];

    char* ws = (char*)d_ws;
    size_t off = 0;
    auto alloc = [&](size_t bytes) -> void* {
        void* p = ws + off;
        off += (bytes + 255) & ~(size_t)255;
        return p;
    };
    u16* ctx = (u16*)alloc((size_t)B_ROWS * CTX_PAD * 2);
    u16* x1  = (u16*)alloc((size_t)B_ROWS * 2048 * 2);
    u16* x2  = (u16*)alloc((size_t)B_ROWS * 1024 * 2);
    u16* x3  = (u16*)alloc((size_t)B_ROWS * 1024 * 2);
    u16* x4  = (u16*)alloc((size_t)B_ROWS * 512 * 2);
    u16* W1t = (u16*)alloc((size_t)2048 * 5184 * 2);
    u16* W2t = (u16*)alloc((size_t)1024 * 7232 * 2);
    u16* W3t = (u16*)alloc((size_t)1024 * 6208 * 2);
    u16* W4t = (u16*)alloc((size_t)512  * 6208 * 2);
    u16* W5t = (u16*)alloc((size_t)1024 * 512  * 2);

    // Stage 1: bf16 conversions (ctx assembly + weight transposes)
    build_ctx<<<dim3((CTX_PAD / 2 + 255) / 256, B_ROWS), 256, 0, stream>>>(state, ti, action, ctx);
    wconv<<<dim3(81, 32),  256, 0, stream>>>(W_l1, W1t, 5124, 5184, 2048);
    wconv<<<dim3(113, 16), 256, 0, stream>>>(W_l2, W2t, 7172, 7232, 1024);
    wconv<<<dim3(97, 16),  256, 0, stream>>>(W_l3, W3t, 6148, 6208, 1024);
    wconv<<<dim3(97, 8),   256, 0, stream>>>(W_l4, W4t, 6148, 6208, 512);
    wconv<<<dim3(8, 16),   256, 0, stream>>>(W_l5, W5t, 512, 512, 1024);

    // Stage 2: the live GEMM chain (concat folded in as split-K A sources)
    // L1: x1 = ctx @ W1 + b1        [8192,2048], K=5184  (256 blocks, 1/CU)
    gemm8<256, 256, true><<<dim3(32, 8), 512, 0, stream>>>(
        ctx, CTX_PAD, CTX_PAD, nullptr, 0, W1t, 5184, 5184, b_l1, x1, 2048);
    // L2: x2 = [x1|ctx] @ W2 + b2  [8192,1024], K=7232  (256 blocks, 1/CU)
    gemm8<256, 128, true><<<dim3(32, 8), 512, 0, stream>>>(
        x1, 2048, 2048, ctx, CTX_PAD, W2t, 7232, 7232, b_l2, x2, 1024);
    // L3: x3 = [x2|ctx] @ W3 + b3  [8192,1024], K=6208  (256 blocks, 1/CU)
    gemm8<256, 128, true><<<dim3(32, 8), 512, 0, stream>>>(
        x2, 1024, 1024, ctx, CTX_PAD, W3t, 6208, 6208, b_l3, x3, 1024);
    // L4: x4 = [x3|ctx] @ W4 + b4  [8192,512],  K=6208  (256 blocks, old 2ph)
    gemm_bias<128, 128, 2, 2, true><<<dim3(64, 4), 256, 0, stream>>>(
        x3, 1024, 1024, ctx, CTX_PAD, W4t, 6208, 6208, b_l4, x4, 512);
    // L5: out = x4 @ W5 + b5 (fp32) [8192,1024], K=512  (256 blocks, 1/CU)
    gemm8<256, 128, false><<<dim3(32, 8), 512, 0, stream>>>(
        x4, 512, 512, nullptr, 0, W5t, 512, 512, b_l5, d_out, 1024);
}

// Round 6
// 1035.088 us; speedup vs baseline: 1.0249x; 1.0249x over previous
//
#include <hip/hip_runtime.h>
#include <hip/hip_bf16.h>
#include <stdint.h>

// Problem constants
#define B_ROWS   8192
#define CTX_REAL 5124     // 4096 state + 4 task + 1024 action
#define CTX_PAD  5184     // padded to multiple of 64 (81*64), pad cols zeroed

typedef unsigned short u16;
typedef __attribute__((ext_vector_type(8))) short short8;
typedef __attribute__((ext_vector_type(16))) float f32x16;

#define AS1 __attribute__((address_space(1)))
#define AS3 __attribute__((address_space(3)))

__device__ __forceinline__ u16 f2bf(float f) {
    union { float f; uint32_t u; } v; v.f = f;
    uint32_t u = v.u;
    uint32_t r = 0x7fffu + ((u >> 16) & 1u);   // round-to-nearest-even
    return (u16)((u + r) >> 16);
}

// XCD-locality block remap (T1, modulo form to match round-robin dispatch):
// linear b -> (row, col) with col == b&7 so every block on XCD x works on
// output-column-panel x -> that B-panel (<=2.65MB) stays L2-resident per XCD.
// GY==8: col=b&7, row=b>>3 (bijective: b=row*8+col).
// GY==4: col=(b&7)&3, row=(b>>3)*2+((b&7)>>2) (bijective: the two b&7 values
//        {c,c+4} mapping to col c get distinct row parities).
__device__ __forceinline__ void xcd_map(int GY, int& row, int& col) {
    const int b = blockIdx.x + gridDim.x * blockIdx.y;
    if (GY == 8) { col = b & 7;        row = b >> 3; }
    else         { col = (b & 7) & 3;  row = ((b >> 3) << 1) + ((b & 7) >> 2); }
}

// ---------------------------------------------------------------------------
// ctx = bf16([state | task_indicator | action | zeros]) , [B_ROWS][CTX_PAD]
// ---------------------------------------------------------------------------
__global__ void build_ctx(const float* __restrict__ state,
                          const float* __restrict__ ti,
                          const float* __restrict__ action,
                          u16* __restrict__ ctx) {
    const int row = blockIdx.y;
    const int c2  = blockIdx.x * blockDim.x + threadIdx.x;
    const int col = c2 * 2;
    if (col >= CTX_PAD) return;

    float v0, v1;
    {
        int c = col;
        v0 = (c < 4096) ? state[(size_t)row * 4096 + c]
           : (c < 4100) ? ti[(size_t)row * 4 + (c - 4096)]
           : (c < 5124) ? action[(size_t)row * 1024 + (c - 4100)]
           : 0.0f;
        c = col + 1;
        v1 = (c < 4096) ? state[(size_t)row * 4096 + c]
           : (c < 4100) ? ti[(size_t)row * 4 + (c - 4096)]
           : (c < 5124) ? action[(size_t)row * 1024 + (c - 4100)]
           : 0.0f;
    }
    uint32_t packed = (uint32_t)f2bf(v0) | ((uint32_t)f2bf(v1) << 16);
    *(uint32_t*)&ctx[(size_t)row * CTX_PAD + col] = packed;
}

// ---------------------------------------------------------------------------
// Wt[n][k] = bf16(W[k][n]) for k < K_real, else 0.   W: [K_real][N] fp32,
// Wt: [N][Kpad] bf16.  64x64 LDS-tiled transpose.
// ---------------------------------------------------------------------------
__global__ void wconv(const float* __restrict__ W, u16* __restrict__ Wt,
                      int K_real, int Kpad, int N) {
    __shared__ float tile[64][65];
    const int k0 = blockIdx.x * 64;
    const int n0 = blockIdx.y * 64;
    const int t  = threadIdx.x;
#pragma unroll
    for (int i = 0; i < 16; ++i) {
        int idx = i * 256 + t;
        int r = idx >> 6, c = idx & 63;       // r: k offset, c: n offset
        int k = k0 + r;
        tile[r][c] = (k < K_real) ? W[(size_t)k * N + n0 + c] : 0.0f;
    }
    __syncthreads();
#pragma unroll
    for (int i = 0; i < 16; ++i) {
        int idx = i * 256 + t;
        int rn = idx >> 6, ck = idx & 63;     // rn: n offset, ck: k offset
        Wt[(size_t)(n0 + rn) * Kpad + k0 + ck] = f2bf(tile[ck][rn]);
    }
}

// ---------------------------------------------------------------------------
// 2-phase 128x128 template (verified: L2/L3-class layers faster here at
// 2 blocks/CU than gemm8 at 1 block/CU — per-CU MLP matters in the
// ingest-bound regime).  R6: + XCD block remap (GY runtime 8 or 4).
// ---------------------------------------------------------------------------
template <int TM, int TN, int MW, int NW, bool OUT_BF16>
__global__ __launch_bounds__(256, 2)
void gemm_bias(const u16* __restrict__ A1, int lda1, int K1,
               const u16* __restrict__ A2, int lda2,
               const u16* __restrict__ Bt, int ldb, int Ktot,
               const float* __restrict__ bias,
               void* __restrict__ Cout, int ldc) {
    constexpr int FI = TM / MW / 32;
    constexpr int FJ = TN / NW / 32;
    __shared__ u16 tA[2][TM * 64];
    __shared__ u16 tB[2][TN * 64];

    const int t    = threadIdx.x;
    const int wave = t >> 6;
    const int lane = t & 63;
    const int l32  = lane & 31;
    const int half = lane >> 5;
    const int lswz = lane & 7;
    const int wr   = (wave / NW) * (TM / MW);
    const int wc   = (wave % NW) * (TN / NW);

    int brow, bcol;
    xcd_map((int)gridDim.y, brow, bcol);
    const int rowBase = brow * TM;
    const int colBase = bcol * TN;

    const int srow = t >> 3;
    const int scol = ((t & 7) ^ (srow & 7)) * 8;

    const u16* gA1 = A1 + (size_t)(rowBase + srow) * lda1 + scol;
    const u16* gA2 = A2 ? (A2 + (size_t)(rowBase + srow) * lda2 + scol) : gA1;
    const u16* gB  = Bt + (size_t)(colBase + srow) * ldb + scol;

    f32x16 acc[FI][FJ] = {};

    const int nKt = Ktot >> 6;

    auto stage = [&](int kt, int buf) {
        const int k0 = kt << 6;
        const u16* srcA;
        int strideA;
        if (k0 < K1) { srcA = gA1 + k0;        strideA = lda1; }
        else         { srcA = gA2 + (k0 - K1); strideA = lda2; }
        const u16* srcB = gB + k0;
        char* ldsA = (char*)tA[buf] + wave * 1024;
        char* ldsB = (char*)tB[buf] + wave * 1024;
#pragma unroll
        for (int it = 0; it < TM / 32; ++it)
            __builtin_amdgcn_global_load_lds(
                (AS1 const void*)(srcA + (size_t)(it * 32) * strideA),
                (AS3 void*)(ldsA + it * 4096), 16, 0, 0);
#pragma unroll
        for (int it = 0; it < TN / 32; ++it)
            __builtin_amdgcn_global_load_lds(
                (AS1 const void*)(srcB + (size_t)(it * 32) * ldb),
                (AS3 void*)(ldsB + it * 4096), 16, 0, 0);
    };

    stage(0, 0);
    __syncthreads();

    for (int kt = 0; kt < nKt; ++kt) {
        const int buf = kt & 1;
        if (kt + 1 < nKt) stage(kt + 1, buf ^ 1);

        const u16* tAw = tA[buf] + wr * 64;
        const u16* tBw = tB[buf] + wc * 64;
#pragma unroll
        for (int ks = 0; ks < 4; ++ks) {
            const int kchunk = ks * 2 + half;
            const int swz    = (kchunk ^ lswz) * 8;
            short8 a[FI], b[FJ];
#pragma unroll
            for (int i = 0; i < FI; ++i)
                a[i] = *(const short8*)(tAw + (i * 32 + l32) * 64 + swz);
#pragma unroll
            for (int j = 0; j < FJ; ++j)
                b[j] = *(const short8*)(tBw + (j * 32 + l32) * 64 + swz);
#pragma unroll
            for (int i = 0; i < FI; ++i)
#pragma unroll
                for (int j = 0; j < FJ; ++j)
                    acc[i][j] = __builtin_amdgcn_mfma_f32_32x32x16_bf16(
                        a[i], b[j], acc[i][j], 0, 0, 0);
        }
        __syncthreads();
    }

    if (OUT_BF16) {
        u16* C = (u16*)Cout;
#pragma unroll
        for (int i = 0; i < FI; ++i) {
            const int rbase = rowBase + wr + i * 32 + 4 * half;
#pragma unroll
            for (int j = 0; j < FJ; ++j) {
                const int c = colBase + wc + j * 32 + l32;
                const float bb = bias[c];
#pragma unroll
                for (int reg = 0; reg < 16; ++reg) {
                    const int r = rbase + (reg & 3) + 8 * (reg >> 2);
                    C[(size_t)r * ldc + c] = f2bf(acc[i][j][reg] + bb);
                }
            }
        }
    } else {
        float* C = (float*)Cout;
#pragma unroll
        for (int i = 0; i < FI; ++i) {
            const int rbase = rowBase + wr + i * 32 + 4 * half;
#pragma unroll
            for (int j = 0; j < FJ; ++j) {
                const int c = colBase + wc + j * 32 + l32;
                const float bb = bias[c];
#pragma unroll
                for (int reg = 0; reg < 16; ++reg) {
                    const int r = rbase + (reg & 3) + 8 * (reg >> 2);
                    C[(size_t)r * ldc + c] = acc[i][j][reg] + bb;
                }
            }
        }
    }
}

// ---------------------------------------------------------------------------
// 8-wave counted-vmcnt template (kept for L1: 256x256 halves A-side L3
// traffic vs 128x128 at equal measured time).  R6: + XCD block remap (GY=8).
// ---------------------------------------------------------------------------
template <int BM, int BN, bool OUT_BF16>
__global__ __launch_bounds__(512, 2)
void gemm8(const u16* __restrict__ A1, int lda1, int K1,
           const u16* __restrict__ A2, int lda2,
           const u16* __restrict__ Bt, int ldb, int Ktot,
           const float* __restrict__ bias,
           void* __restrict__ Cout, int ldc) {
    constexpr int FI  = BM / 64;
    constexpr int FJ  = BN / 128;
    constexpr int LPA = BM / 64;
    constexpr int LPB = BN / 64;
    constexpr int LPT = LPA + LPB;
    static_assert(LPT == 8 || LPT == 6, "vmcnt literal dispatch");

    __shared__ u16 tA[2][BM * 64];
    __shared__ u16 tB[2][BN * 64];

    const int t    = threadIdx.x;
    const int wave = t >> 6;
    const int lane = t & 63;
    const int l32  = lane & 31;
    const int half = lane >> 5;
    const int lswz = lane & 7;
    const int wr   = (wave >> 2) * (BM / 2);
    const int wc   = (wave & 3) * (BN / 4);

    int brow, bcol;
    xcd_map(8, brow, bcol);
    const int rowBase = brow * BM;
    const int colBase = bcol * BN;

    const int srow = t >> 3;
    const int scol = ((t & 7) ^ (srow & 7)) * 8;

    const u16* gA1 = A1 + (size_t)(rowBase + srow) * lda1 + scol;
    const u16* gA2 = A2 ? (A2 + (size_t)(rowBase + srow) * lda2 + scol) : gA1;
    const u16* gB  = Bt + (size_t)(colBase + srow) * ldb + scol;

    auto stage = [&](int kt, int buf) {
        const int k0 = kt << 6;
        const u16* srcA;
        int strideA;
        if (k0 < K1) { srcA = gA1 + k0;        strideA = lda1; }
        else         { srcA = gA2 + (k0 - K1); strideA = lda2; }
        const u16* srcB = gB + k0;
        char* ldsA = (char*)tA[buf] + wave * 1024;
        char* ldsB = (char*)tB[buf] + wave * 1024;
#pragma unroll
        for (int it = 0; it < LPA; ++it)
            __builtin_amdgcn_global_load_lds(
                (AS1 const void*)(srcA + (size_t)(it * 64) * strideA),
                (AS3 void*)(ldsA + it * 8192), 16, 0, 0);
#pragma unroll
        for (int it = 0; it < LPB; ++it)
            __builtin_amdgcn_global_load_lds(
                (AS1 const void*)(srcB + (size_t)(it * 64) * ldb),
                (AS3 void*)(ldsB + it * 8192), 16, 0, 0);
    };

    f32x16 acc[FI][FJ] = {};

    const int nKt = Ktot >> 6;
    stage(0, 0);
    if (nKt > 1) stage(1, 1);

    for (int kt = 0; kt < nKt; ++kt) {
        const int buf = kt & 1;
        if (kt == nKt - 1) {
            asm volatile("s_waitcnt vmcnt(0)" ::: "memory");
        } else if constexpr (LPT == 8) {
            asm volatile("s_waitcnt vmcnt(8)" ::: "memory");
        } else {
            asm volatile("s_waitcnt vmcnt(6)" ::: "memory");
        }
        __builtin_amdgcn_s_barrier();

        const u16* tAw = tA[buf] + wr * 64;
        const u16* tBw = tB[buf] + wc * 64;
#pragma unroll
        for (int ks = 0; ks < 4; ++ks) {
            const int kchunk = ks * 2 + half;
            const int swz    = (kchunk ^ lswz) * 8;
            short8 a[FI], b[FJ];
#pragma unroll
            for (int i = 0; i < FI; ++i)
                a[i] = *(const short8*)(tAw + (i * 32 + l32) * 64 + swz);
#pragma unroll
            for (int j = 0; j < FJ; ++j)
                b[j] = *(const short8*)(tBw + (j * 32 + l32) * 64 + swz);
            __builtin_amdgcn_s_setprio(1);
#pragma unroll
            for (int i = 0; i < FI; ++i)
#pragma unroll
                for (int j = 0; j < FJ; ++j)
                    acc[i][j] = __builtin_amdgcn_mfma_f32_32x32x16_bf16(
                        a[i], b[j], acc[i][j], 0, 0, 0);
            __builtin_amdgcn_s_setprio(0);
            __builtin_amdgcn_s_barrier();
        }

        if (kt + 2 < nKt) stage(kt + 2, buf);
    }

    if (OUT_BF16) {
        u16* C = (u16*)Cout;
#pragma unroll
        for (int i = 0; i < FI; ++i) {
            const int rbase = rowBase + wr + i * 32 + 4 * half;
#pragma unroll
            for (int j = 0; j < FJ; ++j) {
                const int c = colBase + wc + j * 32 + l32;
                const float bb = bias[c];
#pragma unroll
                for (int reg = 0; reg < 16; ++reg) {
                    const int r = rbase + (reg & 3) + 8 * (reg >> 2);
                    C[(size_t)r * ldc + c] = f2bf(acc[i][j][reg] + bb);
                }
            }
        }
    } else {
        float* C = (float*)Cout;
#pragma unroll
        for (int i = 0; i < FI; ++i) {
            const int rbase = rowBase + wr + i * 32 + 4 * half;
#pragma unroll
            for (int j = 0; j < FJ; ++j) {
                const int c = colBase + wc + j * 32 + l32;
                const float bb = bias[c];
#pragma unroll
                for (int reg = 0; reg < 16; ++reg) {
                    const int r = rbase + (reg & 3) + 8 * (reg >> 2);
                    C[(size_t)r * ldc + c] = acc[i][j][reg] + bb;
                }
            }
        }
    }
}

// ---------------------------------------------------------------------------
extern "C" void kernel_launch(void* const* d_in, const int* in_sizes, int n_in,
                              void* d_out, int out_size, void* d_ws, size_t ws_size,
                              hipStream_t stream) {
    const float* state  = (const float*)d_in[0];
    const float* action = (const float*)d_in[1];
    const float* ti     = (const float*)d_in[2];
    // cx branches (d_in[3..18]) are dead wrt output — skipped.
    const float* W_l1 = (const float*)d_in[19]; const float* b_l1 = (const float*)d_in[20];
    const float* W_l2 = (const float*)d_in[21]; const float* b_l2 = (const float*)d_in[22];
    const float* W_l3 = (const float*)d_in[23]; const float* b_l3 = (const float*)d_in[24];
    const float* W_l4 = (const float*)d_in[25]; const float* b_l4 = (const float*)d_in[26];
    const float* W_l5 = (const float*)d_in[27]; const float* b_l5 = (const float*)d_in[28];

    char* ws = (char*)d_ws;
    size_t off = 0;
    auto alloc = [&](size_t bytes) -> void* {
        void* p = ws + off;
        off += (bytes + 255) & ~(size_t)255;
        return p;
    };
    u16* ctx = (u16*)alloc((size_t)B_ROWS * CTX_PAD * 2);
    u16* x1  = (u16*)alloc((size_t)B_ROWS * 2048 * 2);
    u16* x2  = (u16*)alloc((size_t)B_ROWS * 1024 * 2);
    u16* x3  = (u16*)alloc((size_t)B_ROWS * 1024 * 2);
    u16* x4  = (u16*)alloc((size_t)B_ROWS * 512 * 2);
    u16* W1t = (u16*)alloc((size_t)2048 * 5184 * 2);
    u16* W2t = (u16*)alloc((size_t)1024 * 7232 * 2);
    u16* W3t = (u16*)alloc((size_t)1024 * 6208 * 2);
    u16* W4t = (u16*)alloc((size_t)512  * 6208 * 2);
    u16* W5t = (u16*)alloc((size_t)1024 * 512  * 2);

    // Stage 1: bf16 conversions (ctx assembly + weight transposes)
    build_ctx<<<dim3((CTX_PAD / 2 + 255) / 256, B_ROWS), 256, 0, stream>>>(state, ti, action, ctx);
    wconv<<<dim3(81, 32),  256, 0, stream>>>(W_l1, W1t, 5124, 5184, 2048);
    wconv<<<dim3(113, 16), 256, 0, stream>>>(W_l2, W2t, 7172, 7232, 1024);
    wconv<<<dim3(97, 16),  256, 0, stream>>>(W_l3, W3t, 6148, 6208, 1024);
    wconv<<<dim3(97, 8),   256, 0, stream>>>(W_l4, W4t, 6148, 6208, 512);
    wconv<<<dim3(8, 16),   256, 0, stream>>>(W_l5, W5t, 512, 512, 1024);

    // Stage 2: the live GEMM chain (concat folded as split-K A sources),
    // all with XCD-locality block remap (B-panel L2-resident per XCD).
    // L1: x1 = ctx @ W1 + b1        [8192,2048], K=5184  gemm8 256², GY=8
    gemm8<256, 256, true><<<dim3(32, 8), 512, 0, stream>>>(
        ctx, CTX_PAD, CTX_PAD, nullptr, 0, W1t, 5184, 5184, b_l1, x1, 2048);
    // L2: x2 = [x1|ctx] @ W2 + b2  [8192,1024], K=7232  2ph 128², GY=8
    gemm_bias<128, 128, 2, 2, true><<<dim3(64, 8), 256, 0, stream>>>(
        x1, 2048, 2048, ctx, CTX_PAD, W2t, 7232, 7232, b_l2, x2, 1024);
    // L3: x3 = [x2|ctx] @ W3 + b3  [8192,1024], K=6208  2ph 128², GY=8
    gemm_bias<128, 128, 2, 2, true><<<dim3(64, 8), 256, 0, stream>>>(
        x2, 1024, 1024, ctx, CTX_PAD, W3t, 6208, 6208, b_l3, x3, 1024);
    // L4: x4 = [x3|ctx] @ W4 + b4  [8192,512],  K=6208  2ph 128², GY=4
    gemm_bias<128, 128, 2, 2, true><<<dim3(64, 4), 256, 0, stream>>>(
        x3, 1024, 1024, ctx, CTX_PAD, W4t, 6208, 6208, b_l4, x4, 512);
    // L5: out = x4 @ W5 + b5 (fp32) [8192,1024], K=512  2ph 128², GY=8
    gemm_bias<128, 128, 2, 2, false><<<dim3(64, 8), 256, 0, stream>>>(
        x4, 512, 512, nullptr, 0, W5t, 512, 512, b_l5, d_out, 1024);
}

// Round 7
// 936.359 us; speedup vs baseline: 1.1329x; 1.1054x over previous
//
#include <hip/hip_runtime.h>
#include <hip/hip_bf16.h>
#include <stdint.h>

// Problem constants
#define B_ROWS   8192
#define CTX_REAL 5124     // 4096 state + 4 task + 1024 action
#define CTX_PAD  5184     // padded to multiple of 64 (81*64), pad cols zeroed

typedef unsigned short u16;
typedef __attribute__((ext_vector_type(8))) short short8;
typedef __attribute__((ext_vector_type(16))) float f32x16;

#define AS1 __attribute__((address_space(1)))
#define AS3 __attribute__((address_space(3)))

__device__ __forceinline__ u16 f2bf(float f) {
    union { float f; uint32_t u; } v; v.f = f;
    uint32_t u = v.u;
    uint32_t r = 0x7fffu + ((u >> 16) & 1u);   // round-to-nearest-even
    return (u16)((u + r) >> 16);
}

// ---------------------------------------------------------------------------
// ctx = bf16([state | task_indicator | action | zeros]) , [B_ROWS][CTX_PAD]
// ---------------------------------------------------------------------------
__global__ void build_ctx(const float* __restrict__ state,
                          const float* __restrict__ ti,
                          const float* __restrict__ action,
                          u16* __restrict__ ctx) {
    const int row = blockIdx.y;
    const int c2  = blockIdx.x * blockDim.x + threadIdx.x;
    const int col = c2 * 2;
    if (col >= CTX_PAD) return;

    float v0, v1;
    {
        int c = col;
        v0 = (c < 4096) ? state[(size_t)row * 4096 + c]
           : (c < 4100) ? ti[(size_t)row * 4 + (c - 4096)]
           : (c < 5124) ? action[(size_t)row * 1024 + (c - 4100)]
           : 0.0f;
        c = col + 1;
        v1 = (c < 4096) ? state[(size_t)row * 4096 + c]
           : (c < 4100) ? ti[(size_t)row * 4 + (c - 4096)]
           : (c < 5124) ? action[(size_t)row * 1024 + (c - 4100)]
           : 0.0f;
    }
    uint32_t packed = (uint32_t)f2bf(v0) | ((uint32_t)f2bf(v1) << 16);
    *(uint32_t*)&ctx[(size_t)row * CTX_PAD + col] = packed;
}

// ---------------------------------------------------------------------------
// Wt[n][k] = bf16(W[k][n]) for k < K_real, else 0.   W: [K_real][N] fp32,
// Wt: [N][Kpad] bf16.  64x64 LDS-tiled transpose.
// ---------------------------------------------------------------------------
__global__ void wconv(const float* __restrict__ W, u16* __restrict__ Wt,
                      int K_real, int Kpad, int N) {
    __shared__ float tile[64][65];
    const int k0 = blockIdx.x * 64;
    const int n0 = blockIdx.y * 64;
    const int t  = threadIdx.x;
#pragma unroll
    for (int i = 0; i < 16; ++i) {
        int idx = i * 256 + t;
        int r = idx >> 6, c = idx & 63;       // r: k offset, c: n offset
        int k = k0 + r;
        tile[r][c] = (k < K_real) ? W[(size_t)k * N + n0 + c] : 0.0f;
    }
    __syncthreads();
#pragma unroll
    for (int i = 0; i < 16; ++i) {
        int idx = i * 256 + t;
        int rn = idx >> 6, ck = idx & 63;     // rn: n offset, ck: k offset
        Wt[(size_t)(n0 + rn) * Kpad + k0 + ck] = f2bf(tile[ck][rn]);
    }
}

// ---------------------------------------------------------------------------
// 2-phase 128x128 template — exact R2-verified form (956µs pipeline).
// Natural blockIdx mapping (R6's XCD remap doubled FETCH_SIZE, no time win —
// reverted).
// ---------------------------------------------------------------------------
template <int TM, int TN, int MW, int NW, bool OUT_BF16>
__global__ __launch_bounds__(256, 2)
void gemm_bias(const u16* __restrict__ A1, int lda1, int K1,
               const u16* __restrict__ A2, int lda2,
               const u16* __restrict__ Bt, int ldb, int Ktot,
               const float* __restrict__ bias,
               void* __restrict__ Cout, int ldc) {
    constexpr int FI = TM / MW / 32;
    constexpr int FJ = TN / NW / 32;
    __shared__ u16 tA[2][TM * 64];
    __shared__ u16 tB[2][TN * 64];

    const int t    = threadIdx.x;
    const int wave = t >> 6;
    const int lane = t & 63;
    const int l32  = lane & 31;
    const int half = lane >> 5;
    const int lswz = lane & 7;
    const int wr   = (wave / NW) * (TM / MW);
    const int wc   = (wave % NW) * (TN / NW);
    const int rowBase = blockIdx.x * TM;
    const int colBase = blockIdx.y * TN;

    const int srow = t >> 3;
    const int scol = ((t & 7) ^ (srow & 7)) * 8;

    const u16* gA1 = A1 + (size_t)(rowBase + srow) * lda1 + scol;
    const u16* gA2 = A2 ? (A2 + (size_t)(rowBase + srow) * lda2 + scol) : gA1;
    const u16* gB  = Bt + (size_t)(colBase + srow) * ldb + scol;

    f32x16 acc[FI][FJ] = {};

    const int nKt = Ktot >> 6;

    auto stage = [&](int kt, int buf) {
        const int k0 = kt << 6;
        const u16* srcA;
        int strideA;
        if (k0 < K1) { srcA = gA1 + k0;        strideA = lda1; }
        else         { srcA = gA2 + (k0 - K1); strideA = lda2; }
        const u16* srcB = gB + k0;
        char* ldsA = (char*)tA[buf] + wave * 1024;
        char* ldsB = (char*)tB[buf] + wave * 1024;
#pragma unroll
        for (int it = 0; it < TM / 32; ++it)
            __builtin_amdgcn_global_load_lds(
                (AS1 const void*)(srcA + (size_t)(it * 32) * strideA),
                (AS3 void*)(ldsA + it * 4096), 16, 0, 0);
#pragma unroll
        for (int it = 0; it < TN / 32; ++it)
            __builtin_amdgcn_global_load_lds(
                (AS1 const void*)(srcB + (size_t)(it * 32) * ldb),
                (AS3 void*)(ldsB + it * 4096), 16, 0, 0);
    };

    stage(0, 0);
    __syncthreads();

    for (int kt = 0; kt < nKt; ++kt) {
        const int buf = kt & 1;
        if (kt + 1 < nKt) stage(kt + 1, buf ^ 1);

        const u16* tAw = tA[buf] + wr * 64;
        const u16* tBw = tB[buf] + wc * 64;
#pragma unroll
        for (int ks = 0; ks < 4; ++ks) {
            const int kchunk = ks * 2 + half;
            const int swz    = (kchunk ^ lswz) * 8;
            short8 a[FI], b[FJ];
#pragma unroll
            for (int i = 0; i < FI; ++i)
                a[i] = *(const short8*)(tAw + (i * 32 + l32) * 64 + swz);
#pragma unroll
            for (int j = 0; j < FJ; ++j)
                b[j] = *(const short8*)(tBw + (j * 32 + l32) * 64 + swz);
#pragma unroll
            for (int i = 0; i < FI; ++i)
#pragma unroll
                for (int j = 0; j < FJ; ++j)
                    acc[i][j] = __builtin_amdgcn_mfma_f32_32x32x16_bf16(
                        a[i], b[j], acc[i][j], 0, 0, 0);
        }
        __syncthreads();
    }

    if (OUT_BF16) {
        u16* C = (u16*)Cout;
#pragma unroll
        for (int i = 0; i < FI; ++i) {
            const int rbase = rowBase + wr + i * 32 + 4 * half;
#pragma unroll
            for (int j = 0; j < FJ; ++j) {
                const int c = colBase + wc + j * 32 + l32;
                const float bb = bias[c];
#pragma unroll
                for (int reg = 0; reg < 16; ++reg) {
                    const int r = rbase + (reg & 3) + 8 * (reg >> 2);
                    C[(size_t)r * ldc + c] = f2bf(acc[i][j][reg] + bb);
                }
            }
        }
    } else {
        float* C = (float*)Cout;
#pragma unroll
        for (int i = 0; i < FI; ++i) {
            const int rbase = rowBase + wr + i * 32 + 4 * half;
#pragma unroll
            for (int j = 0; j < FJ; ++j) {
                const int c = colBase + wc + j * 32 + l32;
                const float bb = bias[c];
#pragma unroll
                for (int reg = 0; reg < 16; ++reg) {
                    const int r = rbase + (reg & 3) + 8 * (reg >> 2);
                    C[(size_t)r * ldc + c] = acc[i][j][reg] + bb;
                }
            }
        }
    }
}

// ---------------------------------------------------------------------------
// 8-wave counted-vmcnt template, R7: NO intra-tile phase barriers.
// R6 PMC showed the 4-phase barrier lockstep serialized LDS-reads against
// MFMA (wall 6845 cyc/ktile vs max-pipe floor ~3600): phases ADDED read and
// MFMA time.  Now one k-tile = {counted vmcnt gate; s_barrier; all 24
// ds_read_b128 + 32 MFMA, compiler-scheduled (hipcc emits fine-grained
// lgkmcnt interleave — m97 evidence); s_barrier; restage}.  Safety: every
// ds_read is consumed by an MFMA before the closing barrier, so lgkm is
// drained before the restage overwrites the buffer; counted-vmcnt ledger
// unchanged (gate vmcnt(LPT) waits tile kt, leaves kt+1 in flight; last
// tile gates vmcnt(0)).  setprio removed (no role-split left to arbitrate).
// ---------------------------------------------------------------------------
template <int BM, int BN, bool OUT_BF16>
__global__ __launch_bounds__(512, 2)
void gemm8(const u16* __restrict__ A1, int lda1, int K1,
           const u16* __restrict__ A2, int lda2,
           const u16* __restrict__ Bt, int ldb, int Ktot,
           const float* __restrict__ bias,
           void* __restrict__ Cout, int ldc) {
    constexpr int FI  = BM / 64;
    constexpr int FJ  = BN / 128;
    constexpr int LPA = BM / 64;
    constexpr int LPB = BN / 64;
    constexpr int LPT = LPA + LPB;
    static_assert(LPT == 8 || LPT == 6, "vmcnt literal dispatch");

    __shared__ u16 tA[2][BM * 64];
    __shared__ u16 tB[2][BN * 64];

    const int t    = threadIdx.x;
    const int wave = t >> 6;
    const int lane = t & 63;
    const int l32  = lane & 31;
    const int half = lane >> 5;
    const int lswz = lane & 7;
    const int wr   = (wave >> 2) * (BM / 2);
    const int wc   = (wave & 3) * (BN / 4);
    const int rowBase = blockIdx.x * BM;
    const int colBase = blockIdx.y * BN;

    const int srow = t >> 3;
    const int scol = ((t & 7) ^ (srow & 7)) * 8;

    const u16* gA1 = A1 + (size_t)(rowBase + srow) * lda1 + scol;
    const u16* gA2 = A2 ? (A2 + (size_t)(rowBase + srow) * lda2 + scol) : gA1;
    const u16* gB  = Bt + (size_t)(colBase + srow) * ldb + scol;

    auto stage = [&](int kt, int buf) {
        const int k0 = kt << 6;
        const u16* srcA;
        int strideA;
        if (k0 < K1) { srcA = gA1 + k0;        strideA = lda1; }
        else         { srcA = gA2 + (k0 - K1); strideA = lda2; }
        const u16* srcB = gB + k0;
        char* ldsA = (char*)tA[buf] + wave * 1024;
        char* ldsB = (char*)tB[buf] + wave * 1024;
#pragma unroll
        for (int it = 0; it < LPA; ++it)
            __builtin_amdgcn_global_load_lds(
                (AS1 const void*)(srcA + (size_t)(it * 64) * strideA),
                (AS3 void*)(ldsA + it * 8192), 16, 0, 0);
#pragma unroll
        for (int it = 0; it < LPB; ++it)
            __builtin_amdgcn_global_load_lds(
                (AS1 const void*)(srcB + (size_t)(it * 64) * ldb),
                (AS3 void*)(ldsB + it * 8192), 16, 0, 0);
    };

    f32x16 acc[FI][FJ] = {};

    const int nKt = Ktot >> 6;
    stage(0, 0);
    if (nKt > 1) stage(1, 1);

    for (int kt = 0; kt < nKt; ++kt) {
        const int buf = kt & 1;
        if (kt == nKt - 1) {
            asm volatile("s_waitcnt vmcnt(0)" ::: "memory");
        } else if constexpr (LPT == 8) {
            asm volatile("s_waitcnt vmcnt(8)" ::: "memory");
        } else {
            asm volatile("s_waitcnt vmcnt(6)" ::: "memory");
        }
        __builtin_amdgcn_s_barrier();   // tile kt staged (all waves gated)

        const u16* tAw = tA[buf] + wr * 64;
        const u16* tBw = tB[buf] + wc * 64;
#pragma unroll
        for (int ks = 0; ks < 4; ++ks) {
            const int kchunk = ks * 2 + half;
            const int swz    = (kchunk ^ lswz) * 8;
            short8 a[FI], b[FJ];
#pragma unroll
            for (int i = 0; i < FI; ++i)
                a[i] = *(const short8*)(tAw + (i * 32 + l32) * 64 + swz);
#pragma unroll
            for (int j = 0; j < FJ; ++j)
                b[j] = *(const short8*)(tBw + (j * 32 + l32) * 64 + swz);
#pragma unroll
            for (int i = 0; i < FI; ++i)
#pragma unroll
                for (int j = 0; j < FJ; ++j)
                    acc[i][j] = __builtin_amdgcn_mfma_f32_32x32x16_bf16(
                        a[i], b[j], acc[i][j], 0, 0, 0);
        }
        __builtin_amdgcn_s_barrier();   // all reads of buf retired (consumed
                                        // by MFMAs above -> lgkm drained)
        if (kt + 2 < nKt) stage(kt + 2, buf);
    }

    if (OUT_BF16) {
        u16* C = (u16*)Cout;
#pragma unroll
        for (int i = 0; i < FI; ++i) {
            const int rbase = rowBase + wr + i * 32 + 4 * half;
#pragma unroll
            for (int j = 0; j < FJ; ++j) {
                const int c = colBase + wc + j * 32 + l32;
                const float bb = bias[c];
#pragma unroll
                for (int reg = 0; reg < 16; ++reg) {
                    const int r = rbase + (reg & 3) + 8 * (reg >> 2);
                    C[(size_t)r * ldc + c] = f2bf(acc[i][j][reg] + bb);
                }
            }
        }
    } else {
        float* C = (float*)Cout;
#pragma unroll
        for (int i = 0; i < FI; ++i) {
            const int rbase = rowBase + wr + i * 32 + 4 * half;
#pragma unroll
            for (int j = 0; j < FJ; ++j) {
                const int c = colBase + wc + j * 32 + l32;
                const float bb = bias[c];
#pragma unroll
                for (int reg = 0; reg < 16; ++reg) {
                    const int r = rbase + (reg & 3) + 8 * (reg >> 2);
                    C[(size_t)r * ldc + c] = acc[i][j][reg] + bb;
                }
            }
        }
    }
}

// ---------------------------------------------------------------------------
extern "C" void kernel_launch(void* const* d_in, const int* in_sizes, int n_in,
                              void* d_out, int out_size, void* d_ws, size_t ws_size,
                              hipStream_t stream) {
    const float* state  = (const float*)d_in[0];
    const float* action = (const float*)d_in[1];
    const float* ti     = (const float*)d_in[2];
    // cx branches (d_in[3..18]) are dead wrt output — skipped.
    const float* W_l1 = (const float*)d_in[19]; const float* b_l1 = (const float*)d_in[20];
    const float* W_l2 = (const float*)d_in[21]; const float* b_l2 = (const float*)d_in[22];
    const float* W_l3 = (const float*)d_in[23]; const float* b_l3 = (const float*)d_in[24];
    const float* W_l4 = (const float*)d_in[25]; const float* b_l4 = (const float*)d_in[26];
    const float* W_l5 = (const float*)d_in[27]; const float* b_l5 = (const float*)d_in[28];

    char* ws = (char*)d_ws;
    size_t off = 0;
    auto alloc = [&](size_t bytes) -> void* {
        void* p = ws + off;
        off += (bytes + 255) & ~(size_t)255;
        return p;
    };
    u16* ctx = (u16*)alloc((size_t)B_ROWS * CTX_PAD * 2);
    u16* x1  = (u16*)alloc((size_t)B_ROWS * 2048 * 2);
    u16* x2  = (u16*)alloc((size_t)B_ROWS * 1024 * 2);
    u16* x3  = (u16*)alloc((size_t)B_ROWS * 1024 * 2);
    u16* x4  = (u16*)alloc((size_t)B_ROWS * 512 * 2);
    u16* W1t = (u16*)alloc((size_t)2048 * 5184 * 2);
    u16* W2t = (u16*)alloc((size_t)1024 * 7232 * 2);
    u16* W3t = (u16*)alloc((size_t)1024 * 6208 * 2);
    u16* W4t = (u16*)alloc((size_t)512  * 6208 * 2);
    u16* W5t = (u16*)alloc((size_t)1024 * 512  * 2);

    // Stage 1: bf16 conversions (ctx assembly + weight transposes)
    build_ctx<<<dim3((CTX_PAD / 2 + 255) / 256, B_ROWS), 256, 0, stream>>>(state, ti, action, ctx);
    wconv<<<dim3(81, 32),  256, 0, stream>>>(W_l1, W1t, 5124, 5184, 2048);
    wconv<<<dim3(113, 16), 256, 0, stream>>>(W_l2, W2t, 7172, 7232, 1024);
    wconv<<<dim3(97, 16),  256, 0, stream>>>(W_l3, W3t, 6148, 6208, 1024);
    wconv<<<dim3(97, 8),   256, 0, stream>>>(W_l4, W4t, 6148, 6208, 512);
    wconv<<<dim3(8, 16),   256, 0, stream>>>(W_l5, W5t, 512, 512, 1024);

    // Stage 2: the live GEMM chain (concat folded as split-K A sources).
    // L1: x1 = ctx @ W1 + b1        [8192,2048], K=5184  gemm8-nophase 256²
    gemm8<256, 256, true><<<dim3(32, 8), 512, 0, stream>>>(
        ctx, CTX_PAD, CTX_PAD, nullptr, 0, W1t, 5184, 5184, b_l1, x1, 2048);
    // L2: x2 = [x1|ctx] @ W2 + b2  [8192,1024], K=7232  2ph 128² (R2 form)
    gemm_bias<128, 128, 2, 2, true><<<dim3(64, 8), 256, 0, stream>>>(
        x1, 2048, 2048, ctx, CTX_PAD, W2t, 7232, 7232, b_l2, x2, 1024);
    // L3: x3 = [x2|ctx] @ W3 + b3  [8192,1024], K=6208  2ph 128² (R2 form)
    gemm_bias<128, 128, 2, 2, true><<<dim3(64, 8), 256, 0, stream>>>(
        x2, 1024, 1024, ctx, CTX_PAD, W3t, 6208, 6208, b_l3, x3, 1024);
    // L4: x4 = [x3|ctx] @ W4 + b4  [8192,512],  K=6208  2ph 128² (R2 form)
    gemm_bias<128, 128, 2, 2, true><<<dim3(64, 4), 256, 0, stream>>>(
        x3, 1024, 1024, ctx, CTX_PAD, W4t, 6208, 6208, b_l4, x4, 512);
    // L5: out = x4 @ W5 + b5 (fp32) [8192,1024], K=512  2ph 128² (R2 form)
    gemm_bias<128, 128, 2, 2, false><<<dim3(64, 8), 256, 0, stream>>>(
        x4, 512, 512, nullptr, 0, W5t, 512, 512, b_l5, d_out, 1024);
}